// Round 4
// baseline (237.261 us; speedup 1.0000x reference)
//
#include <hip/hip_runtime.h>
#include <hip/hip_bf16.h>
#include <cstdint>

#define B_ROWS 4096
#define DIM 1024
#define NN 8192  // 2*B

typedef __bf16 bf16x8 __attribute__((ext_vector_type(8)));
typedef __bf16 bf16x4 __attribute__((ext_vector_type(4)));
typedef float f32x4 __attribute__((ext_vector_type(4)));

__device__ __forceinline__ float wave_reduce_sum(float v) {
    v += __shfl_xor(v, 1);
    v += __shfl_xor(v, 2);
    v += __shfl_xor(v, 4);
    v += __shfl_xor(v, 8);
    v += __shfl_xor(v, 16);
    v += __shfl_xor(v, 32);
    return v;
}

__device__ __forceinline__ void gld_lds16(const void* g, void* l) {
    __builtin_amdgcn_global_load_lds(
        (__attribute__((address_space(1))) void*)(uintptr_t)g,
        (__attribute__((address_space(3))) void*)l, 16, 0, 0);
}

// Kernel 1: fused L2-normalize (both views) + fp32 positives.
__global__ void norm_pos_kernel(const float* __restrict__ p1,
                                const float* __restrict__ p2,
                                __bf16* __restrict__ rep,
                                float* __restrict__ pos) {
    const int i = blockIdx.x;   // 0..4095
    const int t = threadIdx.x;  // 0..255, one float4 each (DIM=1024)
    float4 a = ((const float4*)(p1 + (size_t)i * DIM))[t];
    float4 b = ((const float4*)(p2 + (size_t)i * DIM))[t];
    float s1 = a.x * a.x + a.y * a.y + a.z * a.z + a.w * a.w;
    float s2 = b.x * b.x + b.y * b.y + b.z * b.z + b.w * b.w;
    float dp = a.x * b.x + a.y * b.y + a.z * b.z + a.w * b.w;
    s1 = wave_reduce_sum(s1);
    s2 = wave_reduce_sum(s2);
    dp = wave_reduce_sum(dp);
    __shared__ float r1[4], r2[4], r3[4];
    const int lane = t & 63, wv = t >> 6;
    if (lane == 0) { r1[wv] = s1; r2[wv] = s2; r3[wv] = dp; }
    __syncthreads();
    const float t1 = r1[0] + r1[1] + r1[2] + r1[3];
    const float t2 = r2[0] + r2[1] + r2[2] + r2[3];
    const float td = r3[0] + r3[1] + r3[2] + r3[3];
    const float sc1 = rsqrtf(t1), sc2 = rsqrtf(t2);
    bf16x4 o1, o2;
    o1.x = (__bf16)(a.x * sc1); o1.y = (__bf16)(a.y * sc1);
    o1.z = (__bf16)(a.z * sc1); o1.w = (__bf16)(a.w * sc1);
    o2.x = (__bf16)(b.x * sc2); o2.y = (__bf16)(b.y * sc2);
    o2.z = (__bf16)(b.z * sc2); o2.w = (__bf16)(b.w * sc2);
    *(bf16x4*)(rep + (size_t)i * DIM + t * 4) = o1;
    *(bf16x4*)(rep + (size_t)(i + B_ROWS) * DIM + t * 4) = o2;
    if (t == 0) pos[i] = td * sc1 * sc2;
}

// Kernel 2: symmetric fused GEMM, upper-triangle tiles (rb <= cb), BK=64.
// XCD-PINNED schedule: HW maps bid -> XCD bid%8 (round-robin). We give
// XCD x exactly the tiles with cb % 8 == x, enumerated rb-major. So each
// XCD's B-tile working set is 8 tiles = 2 MB, static and L2-resident for
// the whole kernel (this is the property that made R1's full grid fast:
// bid = rb*64+cb => XCD = cb%8), while A streams slowly through rb.
__global__ __launch_bounds__(256) void gemm_kernel(const __bf16* __restrict__ rep,
                                                   float* __restrict__ partial) {
    const int x = blockIdx.x & 7;   // XCD slot: owns columns cb ≡ x (mod 8)
    const int j = blockIdx.x >> 3;  // job index within this XCD
    if (j >= 8 * x + 232) return;   // count(x) = sum_{k=0..7} (x+8k+1)

    // rb-major decode within XCD: row rb contributes cbs {cb>=rb, cb%8==x}
    int rem = j, rb = 0, cb;
    for (;;) {
        const int kmin = (rb <= x) ? 0 : ((rb - x + 7) >> 3);
        const int c = 8 - kmin;  // jobs in this row
        if (rem < c) { cb = x + ((kmin + rem) << 3); break; }
        rem -= c; ++rb;
    }

    __shared__ __bf16 As[128 * 64];
    __shared__ __bf16 Bs[128 * 64];
    __shared__ float csum[4][128];
    const int t = threadIdx.x;
    const int lane = t & 63;
    const int wv = t >> 6;    // 0..3
    const int cm = lane & 15; // staging row-in-group / frag m,n index
    const int q = lane >> 4;  // staging 16B seg / frag k-half group

    // staging: group g in {wv, wv+4}, row g*16+cm, 16B seg q, K-half h.
    // LDS fragment-contiguous: every ds_read_b128 is base + lane*16 (conflict-free).
    const __bf16* aS = rep + (size_t)(rb * 128 + wv * 16 + cm) * DIM + q * 8;
    const __bf16* bS = rep + (size_t)(cb * 128 + wv * 16 + cm) * DIM + q * 8;
    __bf16* aD = As + t * 8;
    __bf16* bD = Bs + t * 8;

    f32x4 acc[2][8];
#pragma unroll
    for (int i = 0; i < 2; ++i)
#pragma unroll
        for (int jj = 0; jj < 8; ++jj) acc[i][jj] = (f32x4){0.f, 0.f, 0.f, 0.f};

    for (int kk = 0; kk < DIM / 64; ++kk) {
        const __bf16* a0 = aS + kk * 64;
        const __bf16* b0 = bS + kk * 64;
        // h=0 half (k 0..31)
        gld_lds16(a0, aD);
        gld_lds16(a0 + (size_t)64 * DIM, aD + 2048);
        gld_lds16(b0, bD);
        gld_lds16(b0 + (size_t)64 * DIM, bD + 2048);
        // h=1 half (k 32..63)
        gld_lds16(a0 + 32, aD + 4096);
        gld_lds16(a0 + 32 + (size_t)64 * DIM, aD + 4096 + 2048);
        gld_lds16(b0 + 32, bD + 4096);
        gld_lds16(b0 + 32 + (size_t)64 * DIM, bD + 4096 + 2048);
        __syncthreads();

#pragma unroll
        for (int h = 0; h < 2; ++h) {
            bf16x8 af[2], bfr[8];
#pragma unroll
            for (int mi = 0; mi < 2; ++mi)
                af[mi] = *(const bf16x8*)(As + h * 4096 + (wv * 2 + mi) * 512 + lane * 8);
#pragma unroll
            for (int ni = 0; ni < 8; ++ni)
                bfr[ni] = *(const bf16x8*)(Bs + h * 4096 + ni * 512 + lane * 8);
#pragma unroll
            for (int mi = 0; mi < 2; ++mi)
#pragma unroll
                for (int ni = 0; ni < 8; ++ni)
                    acc[mi][ni] = __builtin_amdgcn_mfma_f32_16x16x32_bf16(
                        af[mi], bfr[ni], acc[mi][ni], 0, 0, 0);
        }
        __syncthreads();
    }

    // Epilogue. C/D layout: col = cm + ni*16, row = wv*32 + mi*16 + q*4 + reg.
    // Row-partials -> partial[cb*NN + grow]; transpose col-partials -> partial[rb*NN + gcol].
    // Row r of block i receives slots {i..63} (row side) and {0..i-1} (transpose): disjoint.
    float colsum[8];
#pragma unroll
    for (int ni = 0; ni < 8; ++ni) colsum[ni] = 0.f;

#pragma unroll
    for (int mi = 0; mi < 2; ++mi) {
#pragma unroll
        for (int reg = 0; reg < 4; ++reg) {
            const int row_l = wv * 32 + mi * 16 + (q << 2) + reg;
            const int grow = rb * 128 + row_l;
            float rs = 0.f;
#pragma unroll
            for (int ni = 0; ni < 8; ++ni) {
                const int gcol = cb * 128 + ni * 16 + cm;
                const float e =
                    (grow == gcol) ? 0.f : __expf(acc[mi][ni][reg] * 2.0f);  // 1/T=2
                rs += e;
                colsum[ni] += e;
            }
            rs += __shfl_xor(rs, 1);
            rs += __shfl_xor(rs, 2);
            rs += __shfl_xor(rs, 4);
            rs += __shfl_xor(rs, 8);
            if (cm == 0) partial[(size_t)cb * NN + grow] = rs;
        }
    }

    if (rb != cb) {
#pragma unroll
        for (int ni = 0; ni < 8; ++ni) {
            colsum[ni] += __shfl_xor(colsum[ni], 16);
            colsum[ni] += __shfl_xor(colsum[ni], 32);
        }
        if (q == 0) {
#pragma unroll
            for (int ni = 0; ni < 8; ++ni) csum[wv][ni * 16 + cm] = colsum[ni];
        }
        __syncthreads();
        if (t < 128) {
            const float c = csum[0][t] + csum[1][t] + csum[2][t] + csum[3][t];
            partial[(size_t)rb * NN + cb * 128 + t] = c;
        }
    }
}

// Kernel 3: per-row denom -> per-row loss -> atomic accumulate into out[0].
// 4-way unrolled accumulators: breaks the 64-deep serial dependent-load chain.
__global__ void reduce_rows_kernel(const float* __restrict__ partial,
                                   const float* __restrict__ pos,
                                   float* __restrict__ out) {
    const int r = blockIdx.x * 256 + threadIdx.x;  // 32 x 256 = 8192
    float s0 = 0.f, s1 = 0.f, s2 = 0.f, s3 = 0.f;
    for (int kb = 0; kb < 64; kb += 4) {
        s0 += partial[(size_t)(kb + 0) * NN + r];
        s1 += partial[(size_t)(kb + 1) * NN + r];
        s2 += partial[(size_t)(kb + 2) * NN + r];
        s3 += partial[(size_t)(kb + 3) * NN + r];
    }
    const float s = (s0 + s1) + (s2 + s3);
    float v = __logf(s) - pos[r & (B_ROWS - 1)] * 2.0f;  // log(denom) - pos/T
    v = wave_reduce_sum(v);
    __shared__ float red[4];
    const int lane = threadIdx.x & 63, wv = threadIdx.x >> 6;
    if (lane == 0) red[wv] = v;
    __syncthreads();
    if (threadIdx.x == 0)
        atomicAdd(out, (red[0] + red[1] + red[2] + red[3]) * (1.0f / NN));
}

extern "C" void kernel_launch(void* const* d_in, const int* in_sizes, int n_in,
                              void* d_out, int out_size, void* d_ws, size_t ws_size,
                              hipStream_t stream) {
    const float* p1 = (const float*)d_in[0];
    const float* p2 = (const float*)d_in[1];
    char* ws = (char*)d_ws;
    __bf16* rep = (__bf16*)ws;                                 // 16 MiB
    float* partial = (float*)(ws + (size_t)16 * 1024 * 1024);  // 2 MiB (64 x 8192)
    float* pos = (float*)(ws + (size_t)18 * 1024 * 1024);      // 16 KiB
    float* out = (float*)d_out;

    hipMemsetAsync(out, 0, sizeof(float), stream);
    norm_pos_kernel<<<B_ROWS, 256, 0, stream>>>(p1, p2, rep, pos);
    gemm_kernel<<<8 * 288, 256, 0, stream>>>(rep, partial);  // 2304; 224 no-op blocks
    reduce_rows_kernel<<<32, 256, 0, stream>>>(partial, pos, out);
}

// Round 5
// 184.791 us; speedup vs baseline: 1.2839x; 1.2839x over previous
//
#include <hip/hip_runtime.h>
#include <hip/hip_bf16.h>
#include <cstdint>

#define B_ROWS 4096
#define DIM 1024
#define NN 8192  // 2*B

typedef __bf16 bf16x8 __attribute__((ext_vector_type(8)));
typedef __bf16 bf16x4 __attribute__((ext_vector_type(4)));
typedef float f32x4 __attribute__((ext_vector_type(4)));

__device__ __forceinline__ float wave_reduce_sum(float v) {
    v += __shfl_xor(v, 1);
    v += __shfl_xor(v, 2);
    v += __shfl_xor(v, 4);
    v += __shfl_xor(v, 8);
    v += __shfl_xor(v, 16);
    v += __shfl_xor(v, 32);
    return v;
}

__device__ __forceinline__ void gld_lds16(const void* g, void* l) {
    __builtin_amdgcn_global_load_lds(
        (__attribute__((address_space(1))) void*)(uintptr_t)g,
        (__attribute__((address_space(3))) void*)l, 16, 0, 0);
}

// Kernel 1: fused L2-normalize (both views) + fp32 positives.
__global__ void norm_pos_kernel(const float* __restrict__ p1,
                                const float* __restrict__ p2,
                                __bf16* __restrict__ rep,
                                float* __restrict__ pos) {
    const int i = blockIdx.x;   // 0..4095
    const int t = threadIdx.x;  // 0..255, one float4 each (DIM=1024)
    float4 a = ((const float4*)(p1 + (size_t)i * DIM))[t];
    float4 b = ((const float4*)(p2 + (size_t)i * DIM))[t];
    float s1 = a.x * a.x + a.y * a.y + a.z * a.z + a.w * a.w;
    float s2 = b.x * b.x + b.y * b.y + b.z * b.z + b.w * b.w;
    float dp = a.x * b.x + a.y * b.y + a.z * b.z + a.w * b.w;
    s1 = wave_reduce_sum(s1);
    s2 = wave_reduce_sum(s2);
    dp = wave_reduce_sum(dp);
    __shared__ float r1[4], r2[4], r3[4];
    const int lane = t & 63, wv = t >> 6;
    if (lane == 0) { r1[wv] = s1; r2[wv] = s2; r3[wv] = dp; }
    __syncthreads();
    const float t1 = r1[0] + r1[1] + r1[2] + r1[3];
    const float t2 = r2[0] + r2[1] + r2[2] + r2[3];
    const float td = r3[0] + r3[1] + r3[2] + r3[3];
    const float sc1 = rsqrtf(t1), sc2 = rsqrtf(t2);
    bf16x4 o1, o2;
    o1.x = (__bf16)(a.x * sc1); o1.y = (__bf16)(a.y * sc1);
    o1.z = (__bf16)(a.z * sc1); o1.w = (__bf16)(a.w * sc1);
    o2.x = (__bf16)(b.x * sc2); o2.y = (__bf16)(b.y * sc2);
    o2.z = (__bf16)(b.z * sc2); o2.w = (__bf16)(b.w * sc2);
    *(bf16x4*)(rep + (size_t)i * DIM + t * 4) = o1;
    *(bf16x4*)(rep + (size_t)(i + B_ROWS) * DIM + t * 4) = o2;
    if (t == 0) pos[i] = td * sc1 * sc2;
}

// Kernel 2: symmetric fused GEMM, upper-triangle tiles (rb <= cb), BK=64.
//
// Staging map (the R1 pattern that coalesces): thread t -> row r = t>>2,
// 16B seg s = t&3, with an XOR swizzle on the GLOBAL seg: g = s ^ ((r>>1)&3).
// Per 4-lane quad the segs are a permutation of one 64B run -> fully
// coalesced global reads. global_load_lds forces LDS slot = t*16B, so the
// fragment reader compensates with the same XOR: seg q ^ ((cm>>1)&3).
// Bank math: slot%8 for lanes 0..15 = {0,4,1,5,2,6,3,7,...} -> exact 2-way
// aliasing (free per m136). Conflict-free AND coalesced.
__global__ __launch_bounds__(256) void gemm_kernel(const __bf16* __restrict__ rep,
                                                   float* __restrict__ partial) {
    // rb-major triangle decode: start(rb) = 64*rb - rb*(rb-1)/2
    const int bid = blockIdx.x;
    int rb = (int)(64.5f - sqrtf(4160.25f - 2.0f * (float)bid));
    while (64 * (rb + 1) - (rb + 1) * rb / 2 <= bid) ++rb;
    while (64 * rb - rb * (rb - 1) / 2 > bid) --rb;
    const int cb = rb + (bid - (64 * rb - rb * (rb - 1) / 2));

    __shared__ __bf16 As[128 * 64];
    __shared__ __bf16 Bs[128 * 64];
    __shared__ float csum[4][128];
    const int t = threadIdx.x;
    const int lane = t & 63;
    const int wv = t >> 6;    // 0..3
    const int cm = lane & 15; // frag m,n index
    const int q = lane >> 4;  // frag 16B-seg index

    // staging: row r = t>>2 (0..63), swizzled global seg g
    const int sr = t >> 2;
    const int sg = (t & 3) ^ ((sr >> 1) & 3);
    const __bf16* aS = rep + (size_t)(rb * 128 + sr) * DIM + sg * 8;
    const __bf16* bS = rep + (size_t)(cb * 128 + sr) * DIM + sg * 8;
    __bf16* aD = As + t * 8;  // HW-forced: wave-uniform base + lane*16
    __bf16* bD = Bs + t * 8;

    // fragment swizzled seg offset (elems): (q ^ ((cm>>1)&3)) * 8
    const int sws = ((q ^ ((cm >> 1) & 3)) << 3);

    f32x4 acc[2][8];
#pragma unroll
    for (int i = 0; i < 2; ++i)
#pragma unroll
        for (int jj = 0; jj < 8; ++jj) acc[i][jj] = (f32x4){0.f, 0.f, 0.f, 0.f};

    for (int kk = 0; kk < DIM / 64; ++kk) {
        const __bf16* a0 = aS + kk * 64;
        const __bf16* b0 = bS + kk * 64;
        // h=0 (k 0..31): rows 0-63 then 64-127
        gld_lds16(a0, aD);
        gld_lds16(a0 + (size_t)64 * DIM, aD + 2048);
        gld_lds16(b0, bD);
        gld_lds16(b0 + (size_t)64 * DIM, bD + 2048);
        // h=1 (k 32..63)
        gld_lds16(a0 + 32, aD + 4096);
        gld_lds16(a0 + 32 + (size_t)64 * DIM, aD + 4096 + 2048);
        gld_lds16(b0 + 32, bD + 4096);
        gld_lds16(b0 + 32 + (size_t)64 * DIM, bD + 4096 + 2048);
        __syncthreads();

#pragma unroll
        for (int h = 0; h < 2; ++h) {
            bf16x8 af[2], bfr[8];
#pragma unroll
            for (int mi = 0; mi < 2; ++mi)
                af[mi] = *(const bf16x8*)(As + h * 4096 +
                                          (wv * 32 + mi * 16 + cm) * 32 + sws);
#pragma unroll
            for (int ni = 0; ni < 8; ++ni)
                bfr[ni] = *(const bf16x8*)(Bs + h * 4096 + (ni * 16 + cm) * 32 + sws);
#pragma unroll
            for (int mi = 0; mi < 2; ++mi)
#pragma unroll
                for (int ni = 0; ni < 8; ++ni)
                    acc[mi][ni] = __builtin_amdgcn_mfma_f32_16x16x32_bf16(
                        af[mi], bfr[ni], acc[mi][ni], 0, 0, 0);
        }
        __syncthreads();
    }

    // Epilogue. C/D layout: col = cm + ni*16, row = wv*32 + mi*16 + q*4 + reg.
    // Row-partials -> partial[cb*NN + grow]; transpose col-partials -> partial[rb*NN + gcol].
    // Row r of block i receives slots {i..63} (row side) and {0..i-1} (transpose): disjoint.
    float colsum[8];
#pragma unroll
    for (int ni = 0; ni < 8; ++ni) colsum[ni] = 0.f;

#pragma unroll
    for (int mi = 0; mi < 2; ++mi) {
#pragma unroll
        for (int reg = 0; reg < 4; ++reg) {
            const int row_l = wv * 32 + mi * 16 + (q << 2) + reg;
            const int grow = rb * 128 + row_l;
            float rs = 0.f;
#pragma unroll
            for (int ni = 0; ni < 8; ++ni) {
                const int gcol = cb * 128 + ni * 16 + cm;
                const float e =
                    (grow == gcol) ? 0.f : __expf(acc[mi][ni][reg] * 2.0f);  // 1/T=2
                rs += e;
                colsum[ni] += e;
            }
            rs += __shfl_xor(rs, 1);
            rs += __shfl_xor(rs, 2);
            rs += __shfl_xor(rs, 4);
            rs += __shfl_xor(rs, 8);
            if (cm == 0) partial[(size_t)cb * NN + grow] = rs;
        }
    }

    if (rb != cb) {
#pragma unroll
        for (int ni = 0; ni < 8; ++ni) {
            colsum[ni] += __shfl_xor(colsum[ni], 16);
            colsum[ni] += __shfl_xor(colsum[ni], 32);
        }
        if (q == 0) {
#pragma unroll
            for (int ni = 0; ni < 8; ++ni) csum[wv][ni * 16 + cm] = colsum[ni];
        }
        __syncthreads();
        if (t < 128) {
            const float c = csum[0][t] + csum[1][t] + csum[2][t] + csum[3][t];
            partial[(size_t)rb * NN + cb * 128 + t] = c;
        }
    }
}

// Kernel 3: per-row denom -> per-row loss -> atomic accumulate into out[0].
__global__ void reduce_rows_kernel(const float* __restrict__ partial,
                                   const float* __restrict__ pos,
                                   float* __restrict__ out) {
    const int r = blockIdx.x * 256 + threadIdx.x;  // 32 x 256 = 8192
    float s0 = 0.f, s1 = 0.f, s2 = 0.f, s3 = 0.f;
    for (int kb = 0; kb < 64; kb += 4) {
        s0 += partial[(size_t)(kb + 0) * NN + r];
        s1 += partial[(size_t)(kb + 1) * NN + r];
        s2 += partial[(size_t)(kb + 2) * NN + r];
        s3 += partial[(size_t)(kb + 3) * NN + r];
    }
    const float s = (s0 + s1) + (s2 + s3);
    float v = __logf(s) - pos[r & (B_ROWS - 1)] * 2.0f;  // log(denom) - pos/T
    v = wave_reduce_sum(v);
    __shared__ float red[4];
    const int lane = threadIdx.x & 63, wv = threadIdx.x >> 6;
    if (lane == 0) red[wv] = v;
    __syncthreads();
    if (threadIdx.x == 0)
        atomicAdd(out, (red[0] + red[1] + red[2] + red[3]) * (1.0f / NN));
}

extern "C" void kernel_launch(void* const* d_in, const int* in_sizes, int n_in,
                              void* d_out, int out_size, void* d_ws, size_t ws_size,
                              hipStream_t stream) {
    const float* p1 = (const float*)d_in[0];
    const float* p2 = (const float*)d_in[1];
    char* ws = (char*)d_ws;
    __bf16* rep = (__bf16*)ws;                                 // 16 MiB
    float* partial = (float*)(ws + (size_t)16 * 1024 * 1024);  // 2 MiB (64 x 8192)
    float* pos = (float*)(ws + (size_t)18 * 1024 * 1024);      // 16 KiB
    float* out = (float*)d_out;

    hipMemsetAsync(out, 0, sizeof(float), stream);
    norm_pos_kernel<<<B_ROWS, 256, 0, stream>>>(p1, p2, rep, pos);
    gemm_kernel<<<2080, 256, 0, stream>>>(rep, partial);
    reduce_rows_kernel<<<32, 256, 0, stream>>>(partial, pos, out);
}

// Round 6
// 158.117 us; speedup vs baseline: 1.5005x; 1.1687x over previous
//
#include <hip/hip_runtime.h>
#include <hip/hip_bf16.h>
#include <cstdint>

#define B_ROWS 4096
#define DIM 1024
#define NN 8192  // 2*B

typedef float f32x4 __attribute__((ext_vector_type(4)));

__device__ __forceinline__ float wave_reduce_sum(float v) {
    v += __shfl_xor(v, 1);
    v += __shfl_xor(v, 2);
    v += __shfl_xor(v, 4);
    v += __shfl_xor(v, 8);
    v += __shfl_xor(v, 16);
    v += __shfl_xor(v, 32);
    return v;
}

__device__ __forceinline__ void gld_lds16(const void* g, void* l) {
    __builtin_amdgcn_global_load_lds(
        (__attribute__((address_space(1))) void*)(uintptr_t)g,
        (__attribute__((address_space(3))) void*)l, 16, 0, 0);
}

// fp32 -> OCP e4m3fn, round-to-nearest-even. Inputs here satisfy |x| < 0.5,
// so no overflow/NaN handling needed. Subnormal cutoff at 2^-6.
__device__ __forceinline__ unsigned char f32_to_e4m3(float x) {
    unsigned int b = __float_as_uint(x);
    unsigned int sign = (b >> 24) & 0x80u;
    unsigned int ab = b & 0x7FFFFFFFu;
    unsigned int out;
    if (__uint_as_float(ab) >= 0.015625f) {
        unsigned int rb = ab + 0x7FFFFu + ((ab >> 20) & 1u);  // RNE at 3 mantissa bits
        int E = (int)(rb >> 23) - 127;
        out = (unsigned int)((E + 7) << 3) | ((rb >> 20) & 7u);
    } else {
        out = (unsigned int)rintf(__uint_as_float(ab) * 512.0f);  // subnormal, 0..8
    }
    return (unsigned char)(out | sign);
}

// Kernel 1: fused L2-normalize (both views) -> fp8 rep, + fp32 positives.
__global__ void norm_pos_kernel(const float* __restrict__ p1,
                                const float* __restrict__ p2,
                                unsigned char* __restrict__ rep,
                                float* __restrict__ pos) {
    const int i = blockIdx.x;   // 0..4095
    const int t = threadIdx.x;  // 0..255, one float4 each (DIM=1024)
    float4 a = ((const float4*)(p1 + (size_t)i * DIM))[t];
    float4 b = ((const float4*)(p2 + (size_t)i * DIM))[t];
    float s1 = a.x * a.x + a.y * a.y + a.z * a.z + a.w * a.w;
    float s2 = b.x * b.x + b.y * b.y + b.z * b.z + b.w * b.w;
    float dp = a.x * b.x + a.y * b.y + a.z * b.z + a.w * b.w;
    s1 = wave_reduce_sum(s1);
    s2 = wave_reduce_sum(s2);
    dp = wave_reduce_sum(dp);
    __shared__ float r1[4], r2[4], r3[4];
    const int lane = t & 63, wv = t >> 6;
    if (lane == 0) { r1[wv] = s1; r2[wv] = s2; r3[wv] = dp; }
    __syncthreads();
    const float t1 = r1[0] + r1[1] + r1[2] + r1[3];
    const float t2 = r2[0] + r2[1] + r2[2] + r2[3];
    const float td = r3[0] + r3[1] + r3[2] + r3[3];
    const float sc1 = rsqrtf(t1), sc2 = rsqrtf(t2);
    uchar4 o1, o2;
    o1.x = f32_to_e4m3(a.x * sc1); o1.y = f32_to_e4m3(a.y * sc1);
    o1.z = f32_to_e4m3(a.z * sc1); o1.w = f32_to_e4m3(a.w * sc1);
    o2.x = f32_to_e4m3(b.x * sc2); o2.y = f32_to_e4m3(b.y * sc2);
    o2.z = f32_to_e4m3(b.z * sc2); o2.w = f32_to_e4m3(b.w * sc2);
    *(uchar4*)(rep + (size_t)i * DIM + t * 4) = o1;
    *(uchar4*)(rep + (size_t)(i + B_ROWS) * DIM + t * 4) = o2;
    if (t == 0) pos[i] = td * sc1 * sc2;
}

// Kernel 2: symmetric fused GEMM in fp8 e4m3, upper-triangle tiles (rb<=cb),
// BK=64, 2x2 wave arrangement (each wave owns a 64x64 subtile, 4x4 frags of
// 16x16x32 fp8 MFMA). LDS traffic per iter: 64 ds_read_b64 + 4 gld_lds calls
// (vs R5: 80 ds_read_b128 + 8 calls) — attacks the measured LDS-pipe bound.
//
// Staging: thread t -> row sr=t>>2 within 64-row call-group, 16B k-seg
// (t&3) XOR-swizzled by (sr>>1)&3; per-quad = one 64 B global run (coalesced).
// Reader compensates with the same XOR; under the 16-lane LDS quantum each
// b64 frag read is 2-way-aliased max (free).
__global__ __launch_bounds__(256) void gemm_kernel(const unsigned char* __restrict__ rep,
                                                   float* __restrict__ partial) {
    // rb-major triangle decode: start(rb) = 64*rb - rb*(rb-1)/2
    const int bid = blockIdx.x;
    int rb = (int)(64.5f - sqrtf(4160.25f - 2.0f * (float)bid));
    while (64 * (rb + 1) - (rb + 1) * rb / 2 <= bid) ++rb;
    while (64 * rb - rb * (rb - 1) / 2 > bid) --rb;
    const int cb = rb + (bid - (64 * rb - rb * (rb - 1) / 2));

    __shared__ __align__(16) unsigned char As[128 * 64];  // 8 KB
    __shared__ __align__(16) unsigned char Bs[128 * 64];  // 8 KB
    const int t = threadIdx.x;
    const int lane = t & 63;
    const int wv = t >> 6;     // 0..3
    const int wr = wv >> 1;    // wave row-half
    const int wc = wv & 1;     // wave col-half
    const int cm = lane & 15;  // frag m,n index
    const int q = lane >> 4;   // frag k-quarter

    // staging source
    const int sr = t >> 2;
    const int sg = (t & 3) ^ ((sr >> 1) & 3);
    const unsigned char* aS = rep + (size_t)(rb * 128 + sr) * DIM + sg * 16;
    const unsigned char* bS = rep + (size_t)(cb * 128 + sr) * DIM + sg * 16;
    unsigned char* aD = As + t * 16;  // HW-forced: wave-uniform base + lane*16
    unsigned char* bD = Bs + t * 16;

    // fragment addressing: row r = half*64 + mi*16 + cm (c = half), 64 B/row;
    // k-piece for (h,q): seg s = 2h + (q>>1) (XOR-swizzled), byte (q&1)*8
    const int fsw = (cm >> 1) & 3;
    const int fbase_off = cm * 64 + (q & 1) * 8;
    int soff[2];  // swizzled seg byte offset per k-half
#pragma unroll
    for (int h = 0; h < 2; ++h) soff[h] = ((2 * h + (q >> 1)) ^ fsw) * 16;

    f32x4 acc[4][4];
#pragma unroll
    for (int i = 0; i < 4; ++i)
#pragma unroll
        for (int j = 0; j < 4; ++j) acc[i][j] = (f32x4){0.f, 0.f, 0.f, 0.f};

    for (int kk = 0; kk < DIM / 64; ++kk) {
        const unsigned char* a0 = aS + kk * 64;
        const unsigned char* b0 = bS + kk * 64;
        gld_lds16(a0, aD);                               // A rows 0..63
        gld_lds16(a0 + (size_t)64 * DIM, aD + 4096);     // A rows 64..127
        gld_lds16(b0, bD);
        gld_lds16(b0 + (size_t)64 * DIM, bD + 4096);
        __syncthreads();

#pragma unroll
        for (int h = 0; h < 2; ++h) {
            long af[4], bfr[4];
#pragma unroll
            for (int mi = 0; mi < 4; ++mi)
                af[mi] = *(const long*)(As + wr * 4096 + mi * 1024 + fbase_off + soff[h]);
#pragma unroll
            for (int ni = 0; ni < 4; ++ni)
                bfr[ni] = *(const long*)(Bs + wc * 4096 + ni * 1024 + fbase_off + soff[h]);
#pragma unroll
            for (int mi = 0; mi < 4; ++mi)
#pragma unroll
                for (int ni = 0; ni < 4; ++ni)
                    acc[mi][ni] = __builtin_amdgcn_mfma_f32_16x16x32_fp8_fp8(
                        af[mi], bfr[ni], acc[mi][ni], 0, 0, 0);
        }
        __syncthreads();
    }

    // Epilogue. C/D layout: col = wc*64 + ni*16 + cm, row = wr*64 + mi*16 + q*4 + reg.
    // Row-partials -> slot 2*cb+wc; transpose col-partials -> slot 2*rb+wr.
    // Row r of block i receives slots {2c,2c+1 : c>=i} ∪ {2c,2c+1 : c<i} = all 128, disjoint.
    float colsum[4];
#pragma unroll
    for (int ni = 0; ni < 4; ++ni) colsum[ni] = 0.f;

#pragma unroll
    for (int mi = 0; mi < 4; ++mi) {
#pragma unroll
        for (int reg = 0; reg < 4; ++reg) {
            const int grow = rb * 128 + wr * 64 + mi * 16 + (q << 2) + reg;
            float rs = 0.f;
#pragma unroll
            for (int ni = 0; ni < 4; ++ni) {
                const int gcol = cb * 128 + wc * 64 + ni * 16 + cm;
                const float e =
                    (grow == gcol) ? 0.f : __expf(acc[mi][ni][reg] * 2.0f);  // 1/T=2
                rs += e;
                colsum[ni] += e;
            }
            rs += __shfl_xor(rs, 1);
            rs += __shfl_xor(rs, 2);
            rs += __shfl_xor(rs, 4);
            rs += __shfl_xor(rs, 8);
            if (cm == 0) partial[(size_t)(2 * cb + wc) * NN + grow] = rs;
        }
    }

    if (rb != cb) {
#pragma unroll
        for (int ni = 0; ni < 4; ++ni) {
            colsum[ni] += __shfl_xor(colsum[ni], 16);  // fold q
            colsum[ni] += __shfl_xor(colsum[ni], 32);
        }
        if (q == 0) {
#pragma unroll
            for (int ni = 0; ni < 4; ++ni)
                partial[(size_t)(2 * rb + wr) * NN + cb * 128 + wc * 64 + ni * 16 + cm] =
                    colsum[ni];
        }
    }
}

// Kernel 3: per-row denom (128 slots) -> per-row loss -> atomic into out[0].
__global__ void reduce_rows_kernel(const float* __restrict__ partial,
                                   const float* __restrict__ pos,
                                   float* __restrict__ out) {
    const int r = blockIdx.x * 256 + threadIdx.x;  // 32 x 256 = 8192
    float s0 = 0.f, s1 = 0.f, s2 = 0.f, s3 = 0.f;
    for (int kb = 0; kb < 128; kb += 4) {
        s0 += partial[(size_t)(kb + 0) * NN + r];
        s1 += partial[(size_t)(kb + 1) * NN + r];
        s2 += partial[(size_t)(kb + 2) * NN + r];
        s3 += partial[(size_t)(kb + 3) * NN + r];
    }
    const float s = (s0 + s1) + (s2 + s3);
    float v = __logf(s) - pos[r & (B_ROWS - 1)] * 2.0f;  // log(denom) - pos/T
    v = wave_reduce_sum(v);
    __shared__ float red[4];
    const int lane = threadIdx.x & 63, wv = threadIdx.x >> 6;
    if (lane == 0) red[wv] = v;
    __syncthreads();
    if (threadIdx.x == 0)
        atomicAdd(out, (red[0] + red[1] + red[2] + red[3]) * (1.0f / NN));
}

extern "C" void kernel_launch(void* const* d_in, const int* in_sizes, int n_in,
                              void* d_out, int out_size, void* d_ws, size_t ws_size,
                              hipStream_t stream) {
    const float* p1 = (const float*)d_in[0];
    const float* p2 = (const float*)d_in[1];
    char* ws = (char*)d_ws;
    unsigned char* rep = (unsigned char*)ws;                  // 8 MiB (fp8)
    float* partial = (float*)(ws + (size_t)8 * 1024 * 1024);  // 4 MiB (128 x 8192)
    float* pos = (float*)(ws + (size_t)12 * 1024 * 1024);     // 16 KiB
    float* out = (float*)d_out;

    hipMemsetAsync(out, 0, sizeof(float), stream);
    norm_pos_kernel<<<B_ROWS, 256, 0, stream>>>(p1, p2, rep, pos);
    gemm_kernel<<<2080, 256, 0, stream>>>(rep, partial);
    reduce_rows_kernel<<<32, 256, 0, stream>>>(partial, pos, out);
}

// Round 7
// 150.214 us; speedup vs baseline: 1.5795x; 1.0526x over previous
//
#include <hip/hip_runtime.h>
#include <hip/hip_bf16.h>
#include <cstdint>

#define B_ROWS 4096
#define DIM 1024
#define NN 8192  // 2*B

typedef float f32x4 __attribute__((ext_vector_type(4)));
typedef long lx2 __attribute__((ext_vector_type(2)));

__device__ __forceinline__ float wave_reduce_sum(float v) {
    v += __shfl_xor(v, 1);
    v += __shfl_xor(v, 2);
    v += __shfl_xor(v, 4);
    v += __shfl_xor(v, 8);
    v += __shfl_xor(v, 16);
    v += __shfl_xor(v, 32);
    return v;
}

__device__ __forceinline__ void gld_lds16(const void* g, void* l) {
    __builtin_amdgcn_global_load_lds(
        (__attribute__((address_space(1))) void*)(uintptr_t)g,
        (__attribute__((address_space(3))) void*)l, 16, 0, 0);
}

// fp32 -> OCP e4m3fn, round-to-nearest-even. Inputs here satisfy |x| < 0.5,
// so no overflow/NaN handling needed. Subnormal cutoff at 2^-6.
__device__ __forceinline__ unsigned char f32_to_e4m3(float x) {
    unsigned int b = __float_as_uint(x);
    unsigned int sign = (b >> 24) & 0x80u;
    unsigned int ab = b & 0x7FFFFFFFu;
    unsigned int out;
    if (__uint_as_float(ab) >= 0.015625f) {
        unsigned int rb = ab + 0x7FFFFu + ((ab >> 20) & 1u);  // RNE at 3 mantissa bits
        int E = (int)(rb >> 23) - 127;
        out = (unsigned int)((E + 7) << 3) | ((rb >> 20) & 7u);
    } else {
        out = (unsigned int)rintf(__uint_as_float(ab) * 512.0f);  // subnormal, 0..8
    }
    return (unsigned char)(out | sign);
}

// Kernel 1: fused L2-normalize (both views) -> fp8 rep, + fp32 positives.
__global__ void norm_pos_kernel(const float* __restrict__ p1,
                                const float* __restrict__ p2,
                                unsigned char* __restrict__ rep,
                                float* __restrict__ pos) {
    const int i = blockIdx.x;   // 0..4095
    const int t = threadIdx.x;  // 0..255, one float4 each (DIM=1024)
    float4 a = ((const float4*)(p1 + (size_t)i * DIM))[t];
    float4 b = ((const float4*)(p2 + (size_t)i * DIM))[t];
    float s1 = a.x * a.x + a.y * a.y + a.z * a.z + a.w * a.w;
    float s2 = b.x * b.x + b.y * b.y + b.z * b.z + b.w * b.w;
    float dp = a.x * b.x + a.y * b.y + a.z * b.z + a.w * b.w;
    s1 = wave_reduce_sum(s1);
    s2 = wave_reduce_sum(s2);
    dp = wave_reduce_sum(dp);
    __shared__ float r1[4], r2[4], r3[4];
    const int lane = t & 63, wv = t >> 6;
    if (lane == 0) { r1[wv] = s1; r2[wv] = s2; r3[wv] = dp; }
    __syncthreads();
    const float t1 = r1[0] + r1[1] + r1[2] + r1[3];
    const float t2 = r2[0] + r2[1] + r2[2] + r2[3];
    const float td = r3[0] + r3[1] + r3[2] + r3[3];
    const float sc1 = rsqrtf(t1), sc2 = rsqrtf(t2);
    uchar4 o1, o2;
    o1.x = f32_to_e4m3(a.x * sc1); o1.y = f32_to_e4m3(a.y * sc1);
    o1.z = f32_to_e4m3(a.z * sc1); o1.w = f32_to_e4m3(a.w * sc1);
    o2.x = f32_to_e4m3(b.x * sc2); o2.y = f32_to_e4m3(b.y * sc2);
    o2.z = f32_to_e4m3(b.z * sc2); o2.w = f32_to_e4m3(b.w * sc2);
    *(uchar4*)(rep + (size_t)i * DIM + t * 4) = o1;
    *(uchar4*)(rep + (size_t)(i + B_ROWS) * DIM + t * 4) = o2;
    if (t == 0) pos[i] = td * sc1 * sc2;
}

// Kernel 2: symmetric fused GEMM in fp8 e4m3, upper-triangle tiles (rb<=cb),
// BK=64, 2x2 wave arrangement (each wave owns 64x64, 4x4 frags of 16x16x32).
//
// K-permutation trick: within a BK=64 step, any k-slot bijection applied to
// BOTH A and B leaves the dot product invariant. So each lane reads its
// swizzled 16 B LDS slot ONCE per fragment as ds_read_b128; low 8 B feed
// MFMA call 0, high 8 B call 1. A-lane (m,q) and B-lane (n,q) carry the same
// global k-range, so pairing is consistent. 8 b128 reads per wave per iter
// (vs R6's 16 b64), quarter-wave bank pattern identical to R5's (measured 0
// conflicts), and all fragment addresses are k-invariant (hoisted).
//
// Staging: thread t -> row sr=t>>2, 16B k-seg (t&3) XOR-swizzled by
// (sr>>1)&3; per-quad = one 64 B global run (coalesced). LDS slot forced
// to t*16 by global_load_lds.
__global__ __launch_bounds__(256) void gemm_kernel(const unsigned char* __restrict__ rep,
                                                   float* __restrict__ partial) {
    // rb-major triangle decode: start(rb) = 64*rb - rb*(rb-1)/2
    const int bid = blockIdx.x;
    int rb = (int)(64.5f - sqrtf(4160.25f - 2.0f * (float)bid));
    while (64 * (rb + 1) - (rb + 1) * rb / 2 <= bid) ++rb;
    while (64 * rb - rb * (rb - 1) / 2 > bid) --rb;
    const int cb = rb + (bid - (64 * rb - rb * (rb - 1) / 2));

    __shared__ __align__(16) unsigned char As[128 * 64];  // 8 KB
    __shared__ __align__(16) unsigned char Bs[128 * 64];  // 8 KB
    const int t = threadIdx.x;
    const int lane = t & 63;
    const int wv = t >> 6;     // 0..3
    const int wr = wv >> 1;    // wave row-half
    const int wc = wv & 1;     // wave col-half
    const int cm = lane & 15;  // frag m,n index
    const int q = lane >> 4;   // frag k-quarter

    // staging source
    const int sr = t >> 2;
    const int sg = (t & 3) ^ ((sr >> 1) & 3);
    const unsigned char* aS = rep + (size_t)(rb * 128 + sr) * DIM + sg * 16;
    const unsigned char* bS = rep + (size_t)(cb * 128 + sr) * DIM + sg * 16;
    unsigned char* aD = As + t * 16;  // HW-forced: wave-uniform base + lane*16
    unsigned char* bD = Bs + t * 16;

    // fragment read bases (k-invariant): row cm within 64-row group, slot q^fsw
    const int fsw = (cm >> 1) & 3;
    const unsigned char* aF = As + wr * 4096 + cm * 64 + ((q ^ fsw) << 4);
    const unsigned char* bF = Bs + wc * 4096 + cm * 64 + ((q ^ fsw) << 4);

    f32x4 acc[4][4];
#pragma unroll
    for (int i = 0; i < 4; ++i)
#pragma unroll
        for (int j = 0; j < 4; ++j) acc[i][j] = (f32x4){0.f, 0.f, 0.f, 0.f};

    for (int kk = 0; kk < DIM / 64; ++kk) {
        const unsigned char* a0 = aS + kk * 64;
        const unsigned char* b0 = bS + kk * 64;
        gld_lds16(a0, aD);                            // A rows 0..63
        gld_lds16(a0 + (size_t)64 * DIM, aD + 4096);  // A rows 64..127
        gld_lds16(b0, bD);
        gld_lds16(b0 + (size_t)64 * DIM, bD + 4096);
        __syncthreads();

        lx2 af[4], bf[4];
#pragma unroll
        for (int mi = 0; mi < 4; ++mi) af[mi] = *(const lx2*)(aF + mi * 1024);
#pragma unroll
        for (int ni = 0; ni < 4; ++ni) bf[ni] = *(const lx2*)(bF + ni * 1024);
#pragma unroll
        for (int h = 0; h < 2; ++h)
#pragma unroll
            for (int mi = 0; mi < 4; ++mi)
#pragma unroll
                for (int ni = 0; ni < 4; ++ni)
                    acc[mi][ni] = __builtin_amdgcn_mfma_f32_16x16x32_fp8_fp8(
                        af[mi][h], bf[ni][h], acc[mi][ni], 0, 0, 0);
        __syncthreads();
    }

    // Epilogue. C/D layout: col = wc*64 + ni*16 + cm, row = wr*64 + mi*16 + q*4 + reg.
    // Row-partials -> slot 2*cb+wc; transpose col-partials -> slot 2*rb+wr.
    // Row r of block i receives slots {2c,2c+1 : c>=i} ∪ {2c,2c+1 : c<i} = all 128, disjoint.
    float colsum[4];
#pragma unroll
    for (int ni = 0; ni < 4; ++ni) colsum[ni] = 0.f;

#pragma unroll
    for (int mi = 0; mi < 4; ++mi) {
#pragma unroll
        for (int reg = 0; reg < 4; ++reg) {
            const int grow = rb * 128 + wr * 64 + mi * 16 + (q << 2) + reg;
            float rs = 0.f;
#pragma unroll
            for (int ni = 0; ni < 4; ++ni) {
                const int gcol = cb * 128 + wc * 64 + ni * 16 + cm;
                const float e =
                    (grow == gcol) ? 0.f : __expf(acc[mi][ni][reg] * 2.0f);  // 1/T=2
                rs += e;
                colsum[ni] += e;
            }
            rs += __shfl_xor(rs, 1);
            rs += __shfl_xor(rs, 2);
            rs += __shfl_xor(rs, 4);
            rs += __shfl_xor(rs, 8);
            if (cm == 0) partial[(size_t)(2 * cb + wc) * NN + grow] = rs;
        }
    }

    if (rb != cb) {
#pragma unroll
        for (int ni = 0; ni < 4; ++ni) {
            colsum[ni] += __shfl_xor(colsum[ni], 16);  // fold q
            colsum[ni] += __shfl_xor(colsum[ni], 32);
        }
        if (q == 0) {
#pragma unroll
            for (int ni = 0; ni < 4; ++ni)
                partial[(size_t)(2 * rb + wr) * NN + cb * 128 + wc * 64 + ni * 16 + cm] =
                    colsum[ni];
        }
    }
}

// Kernel 3: per-row denom (128 slots) -> per-row loss -> atomic into out[0].
__global__ void reduce_rows_kernel(const float* __restrict__ partial,
                                   const float* __restrict__ pos,
                                   float* __restrict__ out) {
    const int r = blockIdx.x * 256 + threadIdx.x;  // 32 x 256 = 8192
    float s0 = 0.f, s1 = 0.f, s2 = 0.f, s3 = 0.f;
    for (int kb = 0; kb < 128; kb += 4) {
        s0 += partial[(size_t)(kb + 0) * NN + r];
        s1 += partial[(size_t)(kb + 1) * NN + r];
        s2 += partial[(size_t)(kb + 2) * NN + r];
        s3 += partial[(size_t)(kb + 3) * NN + r];
    }
    const float s = (s0 + s1) + (s2 + s3);
    float v = __logf(s) - pos[r & (B_ROWS - 1)] * 2.0f;  // log(denom) - pos/T
    v = wave_reduce_sum(v);
    __shared__ float red[4];
    const int lane = threadIdx.x & 63, wv = threadIdx.x >> 6;
    if (lane == 0) red[wv] = v;
    __syncthreads();
    if (threadIdx.x == 0)
        atomicAdd(out, (red[0] + red[1] + red[2] + red[3]) * (1.0f / NN));
}

extern "C" void kernel_launch(void* const* d_in, const int* in_sizes, int n_in,
                              void* d_out, int out_size, void* d_ws, size_t ws_size,
                              hipStream_t stream) {
    const float* p1 = (const float*)d_in[0];
    const float* p2 = (const float*)d_in[1];
    char* ws = (char*)d_ws;
    unsigned char* rep = (unsigned char*)ws;                  // 8 MiB (fp8)
    float* partial = (float*)(ws + (size_t)8 * 1024 * 1024);  // 4 MiB (128 x 8192)
    float* pos = (float*)(ws + (size_t)12 * 1024 * 1024);     // 16 KiB
    float* out = (float*)d_out;

    hipMemsetAsync(out, 0, sizeof(float), stream);
    norm_pos_kernel<<<B_ROWS, 256, 0, stream>>>(p1, p2, rep, pos);
    gemm_kernel<<<2080, 256, 0, stream>>>(rep, partial);
    reduce_rows_kernel<<<32, 256, 0, stream>>>(partial, pos, out);
}